// Round 10
// baseline (142.157 us; speedup 1.0000x reference)
//
#include <hip/hip_runtime.h>

#define BLANK 36
#define NEG -1e30f
#define CC 37
#define LOG37 3.6109179126442243f

__device__ __forceinline__ float logaddexp_f(float a, float b) {
    float m = fmaxf(a, b);
    float d = fabsf(a - b);
    return m + __logf(1.0f + __expf(-d));
}

// DPP helpers: shifts/broadcasts on the VALU pipe (NOT ds_bpermute/LDS pipe).
// ctrl: 0x110|n = row_shr:n, 0x142 = row_bcast15 (lane15->16..31, lane47->48..63),
// 0x143 = row_bcast31 (lane31->32..63). bound_ctrl=true -> OOB reads give 0.
#define DPP0(src, ctrl) __builtin_amdgcn_update_dpp(0, (src), (ctrl), 0xf, 0xf, true)
#define DPPM(old, src, ctrl) __builtin_amdgcn_update_dpp((old), (src), (ctrl), 0xf, 0xf, false)

// ============ FAST PATH: fused, linear domain, DPP shifts ==================
// One wave per sample; T chunked by 64; LDS double buffer holds 37*softmax
// probs. Recurrence z' = (z + z[s-1] + k*z[s-2]) * p with the s-shifts done
// by DPP row_shr + bcast15/31 boundary patches -> ZERO LDS ops for shuffles
// (the R9 finding: kernel is LDS-pipe-throughput bound; shuffles, gathers,
// staging all share it at 8 waves/CU). Rescale = DPP max-reduce, also LDS-free.
// Remaining LDS ops/step: 1 prob gather (+ amortized staging/softmax).
__global__ __launch_bounds__(256) void ctc_fused_dpp_kernel(
    const float* __restrict__ logits,        // [B, T, C]
    const int*   __restrict__ targets,       // [B * L]
    const int*   __restrict__ input_lengths, // [B]
    const int*   __restrict__ target_lengths,// [B]
    float*       __restrict__ per_sample,    // [B]
    int B, int T, int L)
{
    __shared__ float lds[4 * 4736];
    const int lane = threadIdx.x & 63;
    const int wib  = threadIdx.x >> 6;
    const int b    = blockIdx.x * 4 + wib;
    if (b >= B) return;

    float* X0 = lds + wib * 4736;
    float* X1 = X0 + 2368;

    const int S = 2 * L + 1;
    const int tlen_s = __builtin_amdgcn_readfirstlane(target_lengths[b]);
    const int ilen_s = __builtin_amdgcn_readfirstlane(input_lengths[b]);
    const int end_s  = 2 * tlen_s;

    int ext_s = BLANK;                 // < CC always -> LDS gathers in-bounds
    if (lane < S && (lane & 1)) ext_s = targets[b * L + (lane >> 1)];
    const int es2 = __shfl_up(ext_s, 2);
    const bool skip_ok = (lane < S) && (lane >= 2) && (ext_s != BLANK) && (ext_s != es2);
    const float kf = skip_ok ? 1.0f : 0.0f;
    const bool valid = lane < (2 * tlen_s + 1);
    const float validm = valid ? 1.0f : 0.0f;

    // row-boundary lanes for the DPP shift patches
    const bool c16 = ((lane & 31) == 16);   // lanes 16,48: a1=z[l-1] via bcast15
    const bool c17 = ((lane & 31) == 17);   // lanes 17,49: a2=z[l-2] via bcast15
    const bool c32 = (lane == 32);          // a1 via bcast31
    const bool c33 = (lane == 33);          // a2 via bcast31

    const float4* src = (const float4*)(logits + (size_t)b * T * CC);

    float z = 0.0f, racc = 0.0f, capv = NEG;

    auto STEP = [&](float p, int tt) {       // p already includes validm
        const int zi  = __float_as_int(z);
        const int s1  = DPP0(zi, 0x111);     // z[s-1], 0 at row starts
        const int s2  = DPP0(zi, 0x112);     // z[s-2]
        const int b15 = DPP0(zi, 0x142);     // z[15]->16..31, z[47]->48..63
        const int b31 = DPP0(zi, 0x143);     // z[31]->32..63
        const int y15 = DPP0(s1, 0x142);     // z[14]->16..31, z[46]->48..63
        const int y31 = DPP0(s1, 0x143);     // z[30]->32..63
        const float a1 = __int_as_float(c16 ? b15 : (c32 ? b31 : s1));
        const float a2 = __int_as_float(c16 ? y15 : (c17 ? b15 : (c32 ? y31 : (c33 ? b31 : s2))));
        z = fmaf(kf, a2, z + a1) * p;
        if (ilen_s == tt + 1)                // wave-uniform scalar branch
            capv = __logf(fmaxf(z, 1e-35f)) + racc - (float)(tt + 1) * LOG37;
    };

    auto RESCALE = [&]() {                   // DPP max-reduce: zero LDS ops
        float m = z;                         // z >= 0 everywhere, invalid=0
        m = fmaxf(m, __int_as_float(DPPM(__float_as_int(m), __float_as_int(m), 0x111)));
        m = fmaxf(m, __int_as_float(DPPM(__float_as_int(m), __float_as_int(m), 0x112)));
        m = fmaxf(m, __int_as_float(DPPM(__float_as_int(m), __float_as_int(m), 0x114)));
        m = fmaxf(m, __int_as_float(DPPM(__float_as_int(m), __float_as_int(m), 0x118)));
        m = fmaxf(m, __int_as_float(DPPM(__float_as_int(m), __float_as_int(m), 0x142)));
        m = fmaxf(m, __int_as_float(DPPM(__float_as_int(m), __float_as_int(m), 0x143)));
        float gm = __shfl(m, 63);            // global max (once per 16 steps)
        gm = fmaxf(gm, 1e-30f);
        z *= (1.0f / gm);
        racc += __logf(gm);
    };

    auto SOFTMAX = [&](float* Xn) {          // in-place row softmax scaled by 37
        float xr[CC];
        const float* row = Xn + lane * CC;
        #pragma unroll
        for (int c2 = 0; c2 < CC; ++c2) xr[c2] = row[c2];
        float m = xr[0];
        #pragma unroll
        for (int c2 = 1; c2 < CC; ++c2) m = fmaxf(m, xr[c2]);
        float ss = 0.0f;
        #pragma unroll
        for (int c2 = 0; c2 < CC; ++c2) { xr[c2] = __expf(xr[c2] - m); ss += xr[c2]; }
        const float inv = 37.0f / ss;
        float* wrow = Xn + lane * CC;
        #pragma unroll
        for (int c2 = 0; c2 < CC; ++c2) wrow[c2] = xr[c2] * inv;
    };

    // ---- prologue: stage + softmax chunk 0 ----
    {
        float4* dst = (float4*)X0;
        #pragma unroll
        for (int k = 0; k < 9; ++k) dst[k * 64 + lane] = src[k * 64 + lane];
        if (lane < 16) dst[576 + lane] = src[576 + lane];   // 592 = 9*64+16
        __builtin_amdgcn_s_waitcnt(0);
        SOFTMAX(X0);
        __builtin_amdgcn_s_waitcnt(0);
    }

    const int NC = T >> 6;
    for (int c = 0; c < NC; ++c) {
        float* Xb = (c & 1) ? X1 : X0;
        const bool more = (c + 1 < NC);

        // (a) issue global loads for chunk c+1 (named regs; hidden by (b))
        float4 f0 = {}, f1 = {}, f2 = {}, f3 = {}, f4 = {},
               f5 = {}, f6 = {}, f7 = {}, f8 = {}, f9 = {};
        if (more) {
            const float4* s2g = src + (size_t)(c + 1) * 592;
            f0 = s2g[lane];       f1 = s2g[64 + lane];  f2 = s2g[128 + lane];
            f3 = s2g[192 + lane]; f4 = s2g[256 + lane]; f5 = s2g[320 + lane];
            f6 = s2g[384 + lane]; f7 = s2g[448 + lane]; f8 = s2g[512 + lane];
            if (lane < 16) f9 = s2g[576 + lane];
        }

        // (b) 64 steps; probs via 4-slot named-register lookahead (1 gather/step)
        const int tbase = c << 6;
        float p0 = Xb[0 * CC + ext_s] * validm;
        float p1 = Xb[1 * CC + ext_s] * validm;
        float p2 = Xb[2 * CC + ext_s] * validm;
        float p3 = Xb[3 * CC + ext_s] * validm;
        float q0, q1, q2, q3;
        int g = 0;
        if (c == 0) {                 // t = 0 init peeled
            z = (lane <= 1) ? p0 : 0.0f;
            if (ilen_s == 1) capv = __logf(fmaxf(z, 1e-35f)) - LOG37;
            q0 = Xb[4 * CC + ext_s] * validm;
            q1 = Xb[5 * CC + ext_s] * validm;
            q2 = Xb[6 * CC + ext_s] * validm;
            q3 = Xb[7 * CC + ext_s] * validm;
            STEP(p1, 1); STEP(p2, 2); STEP(p3, 3);
            p0 = q0; p1 = q1; p2 = q2; p3 = q3;
            g = 1;
        }
        for (; g < 16; ++g) {
            const int r = (g + 1) << 2;
            if (g < 15) {
                q0 = Xb[(r + 0) * CC + ext_s] * validm;
                q1 = Xb[(r + 1) * CC + ext_s] * validm;
                q2 = Xb[(r + 2) * CC + ext_s] * validm;
                q3 = Xb[(r + 3) * CC + ext_s] * validm;
            }
            const int tt = tbase + (g << 2);
            STEP(p0, tt); STEP(p1, tt + 1); STEP(p2, tt + 2); STEP(p3, tt + 3);
            p0 = q0; p1 = q1; p2 = q2; p3 = q3;
            if ((g & 3) == 3) RESCALE();     // every 16 steps (R9-proven cadence)
        }

        // (c) commit staged chunk c+1, softmax rows in place
        if (more) {
            float* Xn = (c & 1) ? X0 : X1;
            float4* dst = (float4*)Xn;
            dst[lane] = f0;       dst[64 + lane] = f1;  dst[128 + lane] = f2;
            dst[192 + lane] = f3; dst[256 + lane] = f4; dst[320 + lane] = f5;
            dst[384 + lane] = f6; dst[448 + lane] = f7; dst[512 + lane] = f8;
            if (lane < 16) dst[576 + lane] = f9;
            __builtin_amdgcn_s_waitcnt(0);
            SOFTMAX(Xn);
            __builtin_amdgcn_s_waitcnt(0);
        }
    }

    // ---- final_ll once ----
    const float e1 = __shfl(capv, end_s);
    const float e2 = __shfl(capv, end_s - 1);
    const float final_v = logaddexp_f(e1, e2);
    if (lane == 0) per_sample[b] = -final_v / (float)tlen_s;
}

// ============ FALLBACK PATH (proven R2 kernels) ============================
__global__ __launch_bounds__(256) void lse_kernel(
    const float* __restrict__ logits, float* __restrict__ denom, int N)
{
    __shared__ float lds[256 * CC];
    const int lane = threadIdx.x & 63;
    const int wib  = threadIdx.x >> 6;
    const int wave = blockIdx.x * 4 + wib;
    const long long row0 = (long long)wave * 64;
    if (row0 >= N) return;
    const int wbase = wib * 64 * CC;
    const float4* src4 = (const float4*)(logits + row0 * CC);
    const long long n4_remaining = ((long long)N * CC - row0 * CC) / 4;
    float4* lds4 = (float4*)(lds + wbase);
    #pragma unroll
    for (int k = 0; k < 10; ++k) {
        const int idx = k * 64 + lane;
        if (idx < 592 && idx < n4_remaining) lds4[idx] = src4[idx];
    }
    __builtin_amdgcn_s_waitcnt(0);
    const long long row = row0 + lane;
    if (row >= N) return;
    const float* x = lds + wbase + lane * CC;
    float m = x[0];
    #pragma unroll
    for (int c = 1; c < CC; ++c) m = fmaxf(m, x[c]);
    float s = 0.0f;
    #pragma unroll
    for (int c = 0; c < CC; ++c) s += __expf(x[c] - m);
    denom[row] = m + __logf(s);
}

__global__ __launch_bounds__(256) void ctc_alpha2_kernel(
    const float* __restrict__ logits, const float* __restrict__ denom,
    const int* __restrict__ targets, const int* __restrict__ input_lengths,
    const int* __restrict__ target_lengths, float* __restrict__ per_sample,
    int B, int T, int L)
{
    const int wave = (int)((blockIdx.x * blockDim.x + threadIdx.x) >> 6);
    const int lane = threadIdx.x & 63;
    if (wave >= B) return;
    const int b = wave;
    const int S = 2 * L + 1;
    const int tlen = target_lengths[b];
    const int ilen = input_lengths[b];
    const int end_idx = 2 * tlen;
    int ext_s = BLANK;
    if (lane < S && (lane & 1)) ext_s = targets[b * L + (lane >> 1)];
    const int ext_sm2 = __shfl_up(ext_s, 2);
    const bool skip_ok = (lane < S) && (lane >= 2) && (ext_s != BLANK) && (ext_s != ext_sm2);
    const bool valid = lane < (2 * tlen + 1);
    const float* lg = logits + (size_t)b * T * CC;
    const float* dn = denom + (size_t)b * T;
    float x_cur = lg[ext_s];
    float d_cur = dn[0];
    float x_nx = (T > 1) ? lg[CC + ext_s] : 0.0f;
    float d_nx = (T > 1) ? dn[1] : 0.0f;
    float final_v = NEG;
    float alpha = (valid && lane <= 1) ? (x_cur - d_cur) : NEG;
    if (ilen == 1) {
        const float e1 = __shfl(alpha, end_idx);
        const float e2 = __shfl(alpha, end_idx - 1);
        final_v = logaddexp_f(e1, e2);
    }
    for (int tt = 1; tt < T; ++tt) {
        x_cur = x_nx; d_cur = d_nx;
        if (tt + 1 < T) {
            x_nx = lg[(size_t)(tt + 1) * CC + ext_s];
            d_nx = dn[tt + 1];
        }
        const float lpe = x_cur - d_cur;
        float a1 = __shfl_up(alpha, 1);
        if (lane == 0) a1 = NEG;
        float a2 = __shfl_up(alpha, 2);
        if (!skip_ok) a2 = NEG;
        const float m = fmaxf(fmaxf(alpha, a1), a2);
        const float s = __expf(alpha - m) + __expf(a1 - m) + __expf(a2 - m);
        const float na = m + __logf(s) + lpe;
        alpha = valid ? na : NEG;
        if (ilen == tt + 1) {
            const float e1 = __shfl(alpha, end_idx);
            const float e2 = __shfl(alpha, end_idx - 1);
            final_v = logaddexp_f(e1, e2);
        }
    }
    if (lane == 0) per_sample[b] = -final_v / (float)tlen;
}

__global__ __launch_bounds__(256) void ctc_alpha_mono_kernel(
    const float* __restrict__ logits, const int* __restrict__ targets,
    const int* __restrict__ input_lengths, const int* __restrict__ target_lengths,
    float* __restrict__ per_sample, int B, int T, int L)
{
    const int wave = (int)((blockIdx.x * blockDim.x + threadIdx.x) >> 6);
    const int lane = threadIdx.x & 63;
    if (wave >= B) return;
    const int b = wave;
    const int S = 2 * L + 1;
    const int tlen = target_lengths[b];
    const int ilen = input_lengths[b];
    const int end_idx = 2 * tlen;
    int ext_s = BLANK;
    if (lane < S && (lane & 1)) ext_s = targets[b * L + (lane >> 1)];
    const int ext_sm2 = __shfl_up(ext_s, 2);
    const bool skip_ok = (lane < S) && (lane >= 2) && (ext_s != BLANK) && (ext_s != ext_sm2);
    const bool valid = lane < (2 * tlen + 1);
    const float* lg = logits + (size_t)b * T * CC;
    float alpha = NEG, final_v = NEG;
    for (int t = 0; t < T; ++t) {
        float x = (lane < CC) ? lg[t * CC + lane] : -3.0e38f;
        float mx = x;
        #pragma unroll
        for (int o = 32; o > 0; o >>= 1) mx = fmaxf(mx, __shfl_xor(mx, o));
        float e = (lane < CC) ? __expf(x - mx) : 0.0f;
        float se = e;
        #pragma unroll
        for (int o = 32; o > 0; o >>= 1) se += __shfl_xor(se, o);
        const float lp = x - mx - __logf(se);
        const float lpe = __shfl(lp, ext_s);
        float newa;
        if (t == 0) {
            newa = (lane <= 1) ? lpe : NEG;
        } else {
            float a1 = __shfl_up(alpha, 1);
            if (lane == 0) a1 = NEG;
            float a2 = __shfl_up(alpha, 2);
            if (!skip_ok) a2 = NEG;
            newa = logaddexp_f(logaddexp_f(alpha, a1), a2) + lpe;
        }
        if (!valid) newa = NEG;
        alpha = newa;
        if (ilen == t + 1) {
            const float e1 = __shfl(alpha, end_idx);
            const float e2 = __shfl(alpha, end_idx - 1);
            final_v = logaddexp_f(e1, e2);
        }
    }
    if (lane == 0) per_sample[b] = -final_v / (float)tlen;
}

// ---------------- Deterministic mean over B samples ------------------------
__global__ __launch_bounds__(256) void reduce_mean_kernel(
    const float* __restrict__ ps, float* __restrict__ out, int B)
{
    float s = 0.0f;
    for (int i = threadIdx.x; i < B; i += 256) s += ps[i];
    #pragma unroll
    for (int o = 32; o > 0; o >>= 1) s += __shfl_xor(s, o);
    __shared__ float sm[4];
    const int w = threadIdx.x >> 6, l = threadIdx.x & 63;
    if (l == 0) sm[w] = s;
    __syncthreads();
    if (threadIdx.x == 0) {
        out[0] = (sm[0] + sm[1] + sm[2] + sm[3]) / (float)B;
    }
}

extern "C" void kernel_launch(void* const* d_in, const int* in_sizes, int n_in,
                              void* d_out, int out_size, void* d_ws, size_t ws_size,
                              hipStream_t stream) {
    const float* logits         = (const float*)d_in[0];
    const int*   targets        = (const int*)d_in[1];
    const int*   input_lengths  = (const int*)d_in[2];
    const int*   target_lengths = (const int*)d_in[3];

    const int B = in_sizes[2];
    const int L = in_sizes[1] / B;
    const int T = in_sizes[0] / (B * CC);
    const long long N = (long long)B * T;

    float* per_sample = (float*)d_ws;
    float* scratch    = per_sample + B;
    float* out        = (float*)d_out;

    const size_t ws_mid = ((size_t)B + (size_t)N) * sizeof(float);
    const int nblocks_alpha = (B * 64 + 255) / 256;
    const long long nwaves = (N + 63) / 64;

    if ((T % 64 == 0) && T >= 64 && L <= 31 && ws_size >= (size_t)B * sizeof(float)) {
        ctc_fused_dpp_kernel<<<(B + 3) / 4, 256, 0, stream>>>(
            logits, targets, input_lengths, target_lengths, per_sample, B, T, L);
    } else if (ws_size >= ws_mid && T >= 2) {
        lse_kernel<<<(int)((nwaves + 3) / 4), 256, 0, stream>>>(logits, scratch, (int)N);
        ctc_alpha2_kernel<<<nblocks_alpha, 256, 0, stream>>>(
            logits, scratch, targets, input_lengths, target_lengths, per_sample, B, T, L);
    } else {
        ctc_alpha_mono_kernel<<<nblocks_alpha, 256, 0, stream>>>(
            logits, targets, input_lengths, target_lengths, per_sample, B, T, L);
    }
    reduce_mean_kernel<<<1, 256, 0, stream>>>(per_sample, out, B);
}